// Round 4
// baseline (858.994 us; speedup 1.0000x reference)
//
#include <hip/hip_runtime.h>

// ---------------------------------------------------------------------------
// HypComEnc: 2-layer hyperbolic GCN encoder + segment mean pool (c = 1)
// N=100000, D0=256, D=128, E=1600000 edges, S=1600 segments
// Round 4: segment-CSR pool (no atomics), half-wave gather, row_scale fused
//          into GEMM1 prologue.
// ---------------------------------------------------------------------------

#define MAXN 0.996f          // 1 - PROJ_EPS
#define CLIPV 0.9999999f     // 1 - 1e-7 (artanh clip)
#define MINNORM 1e-15f

typedef __attribute__((ext_vector_type(8))) short  short8;
typedef __attribute__((ext_vector_type(4))) float  f32x4;
typedef __attribute__((ext_vector_type(4))) unsigned short us4;

__device__ __forceinline__ float wave_sum(float v) {
#pragma unroll
  for (int o = 32; o > 0; o >>= 1) v += __shfl_xor(v, o);
  return v;
}
// sum within each 32-lane half (enough when both halves hold all features)
__device__ __forceinline__ float half_sum(float v) {
#pragma unroll
  for (int o = 16; o > 0; o >>= 1) v += __shfl_xor(v, o);
  return v;
}

__device__ __forceinline__ unsigned short f2bf(float f) {
  unsigned int u = __float_as_uint(f);
  u = (u + 0x7FFFu + ((u >> 16) & 1u)) >> 16;   // RNE
  return (unsigned short)u;
}
__device__ __forceinline__ float bf_lo(unsigned int u) {
  return __uint_as_float(u << 16);
}
__device__ __forceinline__ float bf_hi(unsigned int u) {
  return __uint_as_float(u & 0xFFFF0000u);
}

// --- hb = proj(expmap0(b)), y2 = ||hb||^2 ; 1 block x 64 threads ------------
__global__ void bias_kernel(const float* __restrict__ b,
                            float* __restrict__ hb, float* __restrict__ y2out) {
  int lane = threadIdx.x;
  float b0 = b[lane], b1 = b[lane + 64];
  float ssq = wave_sum(b0 * b0 + b1 * b1);
  float un = fmaxf(sqrtf(ssq), MINNORM);
  float t = tanhf(un);
  float s = t / un;
  float n = t;
  if (n > MAXN) { s *= MAXN / n; n = MAXN; }
  hb[lane] = s * b0;
  hb[lane + 64] = s * b1;
  if (lane == 0) y2out[0] = n * n;
}

// --- generic histogram ------------------------------------------------------
__global__ void hist_kernel(const int* __restrict__ keys, int* __restrict__ cnt,
                            int n) {
  int e = blockIdx.x * 256 + threadIdx.x;
  if (e < n) atomicAdd(&cnt[keys[e]], 1);
}

// multi-block scan: 256 thr x 4 elems/block; bsum = per-block totals
__global__ __launch_bounds__(256) void scan_kernel(const int* __restrict__ in,
                                                   int* __restrict__ out,
                                                   int* __restrict__ bsum, int n) {
  __shared__ int sh[256];
  int t = threadIdx.x;
  int base = blockIdx.x * 1024 + t * 4;
  int v0 = 0, v1 = 0, v2 = 0, v3 = 0;
  if (base + 0 < n) v0 = in[base + 0];
  if (base + 1 < n) v1 = in[base + 1];
  if (base + 2 < n) v2 = in[base + 2];
  if (base + 3 < n) v3 = in[base + 3];
  int s = v0 + v1 + v2 + v3;
  sh[t] = s;
  __syncthreads();
  int run = s;
  for (int o = 1; o < 256; o <<= 1) {
    int add = (t >= o) ? sh[t - o] : 0;
    __syncthreads();
    run += add;
    sh[t] = run;
    __syncthreads();
  }
  int excl = run - s;
  if (base + 0 < n) out[base + 0] = excl;
  if (base + 1 < n) out[base + 1] = excl + v0;
  if (base + 2 < n) out[base + 2] = excl + v0 + v1;
  if (base + 3 < n) out[base + 3] = excl + v0 + v1 + v2;
  if (t == 255 && bsum) bsum[blockIdx.x] = run;
}

__global__ void scan_add_kernel(int* __restrict__ pre, const int* __restrict__ boff,
                                int n, int total) {
  int i = blockIdx.x * 256 + threadIdx.x;
  if (i < n) pre[i] += boff[blockIdx.x >> 2];
  if (i == 0) pre[n] = total;
}

// single-block scan for n <= 2048 (segments)
__global__ __launch_bounds__(256) void sscan_kernel(const int* __restrict__ in,
                                                    int* __restrict__ out, int n) {
  __shared__ int sh[256];
  int t = threadIdx.x;
  int base = t * 8;
  int v[8];
  int s = 0;
#pragma unroll
  for (int i = 0; i < 8; i++) {
    v[i] = (base + i < n) ? in[base + i] : 0;
    s += v[i];
  }
  sh[t] = s;
  __syncthreads();
  int run = s;
  for (int o = 1; o < 256; o <<= 1) {
    int add = (t >= o) ? sh[t - o] : 0;
    __syncthreads();
    run += add;
    sh[t] = run;
    __syncthreads();
  }
  int running = run - s;
#pragma unroll
  for (int i = 0; i < 8; i++) {
    if (base + i < n) out[base + i] = running;
    running += v[i];
  }
  if (t == 255) out[n] = running;
}

__global__ void fill_kernel(const int* __restrict__ erow, const int* __restrict__ ecol,
                            const int* __restrict__ rowptr, int* __restrict__ fill,
                            int* __restrict__ colidx, int E) {
  int e = blockIdx.x * 256 + threadIdx.x;
  if (e >= E) return;
  int r = erow[e];
  int pos = rowptr[r] + atomicAdd(&fill[r], 1);
  colidx[pos] = ecol[e];
}

// place node i into its segment's slot list
__global__ void sfill_kernel(const int* __restrict__ seg,
                             const int* __restrict__ sptr, int* __restrict__ sfil,
                             int* __restrict__ snode, int M) {
  int i = blockIdx.x * 256 + threadIdx.x;
  if (i >= M) return;
  int s = seg[i];
  int pos = sptr[s] + atomicAdd(&sfil[s], 1);
  snode[pos] = i;
}

// --- MFMA GEMM: Out[m][n] = sum_k A[m][k]*W[n][k], n=128, bf16 MFMA ---------
// L1: A = fp32 X; prologue computes f,xn per row, stages bf16(f*x).
// else: A = packed bf16.
template <bool L1>
__global__ __launch_bounds__(256) void gemm_mfma(const void* __restrict__ Xv,
                                                 const float* __restrict__ Wt,
                                                 float* __restrict__ Out,
                                                 float* __restrict__ xnbuf,
                                                 int M, int K) {
  constexpr int GS = 128 * 16 + 16;          // 2064 B group stride
  __shared__ alignas(16) char smem[8 * GS];  // A: groups 0..3, B: groups 4..7
  __shared__ float fsh[128];
  char* sA = smem;
  char* sB = smem + 4 * GS;
  int tid = threadIdx.x;
  int lane = tid & 63;
  int w = tid >> 6;
  int wr = w >> 1, wc = w & 1;
  int m0 = blockIdx.x * 128;

  if constexpr (L1) {
    // per-row f = clipped tanh(||x||)/||x||, xn = min(tanh,MAXN); coalesced:
    // 8 lanes per row, 32 rows per pass, 4 passes.
    const float* X = (const float*)Xv;
#pragma unroll
    for (int pass = 0; pass < 4; pass++) {
      int row = pass * 32 + (tid >> 3);
      int gm = m0 + row;
      float ssq = 0.f;
      if (gm < M) {
        const float* xr = X + (size_t)gm * 256 + (tid & 7) * 4;
#pragma unroll
        for (int i = 0; i < 8; i++) {
          float4 v = *reinterpret_cast<const float4*>(&xr[i * 32]);
          ssq += v.x * v.x + v.y * v.y + v.z * v.z + v.w * v.w;
        }
      }
      ssq += __shfl_xor(ssq, 1);
      ssq += __shfl_xor(ssq, 2);
      ssq += __shfl_xor(ssq, 4);
      if ((tid & 7) == 0) {
        float un = fmaxf(sqrtf(ssq), MINNORM);
        float t = tanhf(un);
        float f, xn;
        if (t > MAXN) { f = MAXN / un; xn = MAXN; }
        else          { f = t / un;    xn = t; }
        fsh[row] = f;
        if (gm < M) xnbuf[gm] = xn;
      }
    }
    __syncthreads();
  }

  f32x4 acc[4][4] = {};
  for (int k0 = 0; k0 < K; k0 += 32) {
#pragma unroll
    for (int j = 0; j < 4; j++) {
      int i = tid + 256 * j;
      int row = i >> 3;
      int koff = (i & 7) * 4;
      int gm = m0 + row;
      us4 av;
      if constexpr (L1) {
        if (gm < M) {
          float f = fsh[row];
          float4 v = *reinterpret_cast<const float4*>(
              &((const float*)Xv)[(size_t)gm * K + k0 + koff]);
          av[0] = f2bf(v.x * f); av[1] = f2bf(v.y * f);
          av[2] = f2bf(v.z * f); av[3] = f2bf(v.w * f);
        } else { av[0] = 0; av[1] = 0; av[2] = 0; av[3] = 0; }
      } else {
        if (gm < M) av = *reinterpret_cast<const us4*>(
            &((const unsigned short*)Xv)[(size_t)gm * K + k0 + koff]);
        else { av[0] = 0; av[1] = 0; av[2] = 0; av[3] = 0; }
      }
      *reinterpret_cast<us4*>(&sA[(koff >> 3) * GS + row * 16 + (koff & 7) * 2]) = av;
      float4 wv = *reinterpret_cast<const float4*>(&Wt[(size_t)row * K + k0 + koff]);
      us4 bv;
      bv[0] = f2bf(wv.x); bv[1] = f2bf(wv.y); bv[2] = f2bf(wv.z); bv[3] = f2bf(wv.w);
      *reinterpret_cast<us4*>(&sB[(koff >> 3) * GS + row * 16 + (koff & 7) * 2]) = bv;
    }
    __syncthreads();
    int g = lane >> 4, r = lane & 15;
    short8 af[4], bfr[4];
#pragma unroll
    for (int mb = 0; mb < 4; mb++)
      af[mb] = *reinterpret_cast<const short8*>(
          &sA[g * GS + (wr * 64 + mb * 16 + r) * 16]);
#pragma unroll
    for (int nb = 0; nb < 4; nb++)
      bfr[nb] = *reinterpret_cast<const short8*>(
          &sB[g * GS + (wc * 64 + nb * 16 + r) * 16]);
#pragma unroll
    for (int mb = 0; mb < 4; mb++)
#pragma unroll
      for (int nb = 0; nb < 4; nb++)
        acc[mb][nb] = __builtin_amdgcn_mfma_f32_16x16x32_bf16(
            af[mb], bfr[nb], acc[mb][nb], 0, 0, 0);
    __syncthreads();
  }
  int cr = lane >> 4, cc = lane & 15;
#pragma unroll
  for (int mb = 0; mb < 4; mb++)
#pragma unroll
    for (int q = 0; q < 4; q++) {
      int gm = m0 + wr * 64 + mb * 16 + cr * 4 + q;
      if (gm >= M) continue;
#pragma unroll
      for (int nb = 0; nb < 4; nb++)
        Out[(size_t)gm * 128 + wc * 64 + nb * 16 + cc] = acc[mb][nb][q];
    }
}

// --- post-GEMM: mobius tail + proj + mobius_add(bias) + proj + logmap0 ------
// G = mx (fp32); xn per row from xnb; HT packed bf16 out.
__global__ void post_gemm_kernel(const float* __restrict__ G,
                                 const float* __restrict__ xnb,
                                 const float* __restrict__ hb,
                                 const float* __restrict__ y2buf,
                                 unsigned int* __restrict__ HT, int M) {
  int row = blockIdx.x * 4 + (threadIdx.x >> 6);
  int lane = threadIdx.x & 63;
  if (row >= M) return;
  float xn = xnb[row];
  float2 g = *reinterpret_cast<const float2*>(&G[(size_t)row * 128 + lane * 2]);
  float mx0 = g.x, mx1 = g.y;
  float mxn = fmaxf(sqrtf(wave_sum(mx0 * mx0 + mx1 * mx1)), MINNORM);
  float art = atanhf(fminf(xn, CLIPV));
  float t = tanhf(mxn / xn * art);
  float s = t / mxn;
  float rn = t;
  if (rn > MAXN) { s *= MAXN / rn; rn = MAXN; }
  float v0 = s * mx0, v1 = s * mx1;
  float x2 = rn * rn;
  float hb0 = hb[lane * 2], hb1 = hb[lane * 2 + 1];
  float y2 = y2buf[0];
  float xy = wave_sum(v0 * hb0 + v1 * hb1);
  float ca = 1.0f + 2.0f * xy + y2;
  float cb = 1.0f - x2;
  float den = fmaxf(1.0f + 2.0f * xy + x2 * y2, MINNORM);
  float h0 = (ca * v0 + cb * hb0) / den;
  float h1 = (ca * v1 + cb * hb1) / den;
  float hn = fmaxf(sqrtf(wave_sum(h0 * h0 + h1 * h1)), MINNORM);
  if (hn > MAXN) { float ps = MAXN / hn; h0 *= ps; h1 *= ps; hn = MAXN; }
  float ls = atanhf(fminf(hn, CLIPV)) / hn;
  HT[(size_t)row * 64 + lane] =
      (unsigned int)f2bf(ls * h0) | ((unsigned int)f2bf(ls * h1) << 16);
}

// --- CSR gather + fused activation, half-wave edge parallel -----------------
// lanes 0-31 take edge p, lanes 32-63 edge p+1; each lane loads uint2
// (4 features). Also writes xn2[row] = ||out row|| for the next GEMM stage.
__global__ void agg_gather_act_kernel(const unsigned int* __restrict__ ht,
                                      const int* __restrict__ rowptr,
                                      const int* __restrict__ colidx,
                                      unsigned int* __restrict__ out,
                                      float* __restrict__ xn2, int M) {
  int row = blockIdx.x * 4 + (threadIdx.x >> 6);
  int lane = threadIdx.x & 63;
  if (row >= M) return;
  int h = lane >> 5;      // half
  int q = lane & 31;      // uint2 slot -> features 4q..4q+3
  const unsigned int* base = ht + q * 2;
  int p = rowptr[row], pe = rowptr[row + 1];
  float a0 = 0.f, a1 = 0.f, a2 = 0.f, a3 = 0.f;
  if ((p & 1) && p < pe) {             // align p to even for int2 loads
    int c = colidx[p];
    uint2 u = *reinterpret_cast<const uint2*>(&base[(size_t)c * 64]);
    if (h == 0) {
      a0 += bf_lo(u.x); a1 += bf_hi(u.x);
      a2 += bf_lo(u.y); a3 += bf_hi(u.y);
    }
    p++;
  }
  for (; p + 2 <= pe; p += 2) {
    int2 cc = *reinterpret_cast<const int2*>(&colidx[p]);
    int c = h ? cc.y : cc.x;
    uint2 u = *reinterpret_cast<const uint2*>(&base[(size_t)c * 64]);
    a0 += bf_lo(u.x); a1 += bf_hi(u.x);
    a2 += bf_lo(u.y); a3 += bf_hi(u.y);
  }
  if (p < pe) {                        // odd tail
    int c = colidx[p];
    uint2 u = *reinterpret_cast<const uint2*>(&base[(size_t)c * 64]);
    if (h == 0) {
      a0 += bf_lo(u.x); a1 += bf_hi(u.x);
      a2 += bf_lo(u.y); a3 += bf_hi(u.y);
    }
  }
  // merge halves (both halves then hold the full sums)
  a0 += __shfl_xor(a0, 32);
  a1 += __shfl_xor(a1, 32);
  a2 += __shfl_xor(a2, 32);
  a3 += __shfl_xor(a3, 32);
  // act chain: proj(expmap0(a)) -> tanh(logmap0(.)) -> proj(expmap0(.))
  float an = fmaxf(sqrtf(half_sum(a0 * a0 + a1 * a1 + a2 * a2 + a3 * a3)), MINNORM);
  float t = tanhf(an);
  float s = t / an;
  float hn = t;
  if (hn > MAXN) { s *= MAXN / hn; hn = MAXN; }
  float ls = atanhf(fminf(hn, CLIPV)) / hn;
  float at0 = tanhf(ls * s * a0);
  float at1 = tanhf(ls * s * a1);
  float at2 = tanhf(ls * s * a2);
  float at3 = tanhf(ls * s * a3);
  float an2 = fmaxf(sqrtf(half_sum(at0 * at0 + at1 * at1 + at2 * at2 + at3 * at3)),
                    MINNORM);
  float t2 = tanhf(an2);
  float s2 = t2 / an2;
  float rn = t2;
  if (t2 > MAXN) { s2 *= MAXN / t2; rn = MAXN; }
  if (h == 0) {
    uint2 o;
    o.x = (unsigned int)f2bf(s2 * at0) | ((unsigned int)f2bf(s2 * at1) << 16);
    o.y = (unsigned int)f2bf(s2 * at2) | ((unsigned int)f2bf(s2 * at3) << 16);
    *reinterpret_cast<uint2*>(&out[(size_t)row * 64 + q * 2]) = o;
    if (q == 0) xn2[row] = rn;
  }
}

// --- segment pool: per-node logmap0(proj(.)) -> mean -> proj(expmap0(.)) ----
__global__ void pool_gather_kernel(const unsigned int* __restrict__ H,
                                   const int* __restrict__ sptr,
                                   const int* __restrict__ snode,
                                   float* __restrict__ out, int S) {
  int s = blockIdx.x * 4 + (threadIdx.x >> 6);
  int lane = threadIdx.x & 63;
  if (s >= S) return;
  int p = sptr[s], pe = sptr[s + 1];
  int cnt = pe - p;
  float m0 = 0.f, m1 = 0.f;
  for (; p < pe; p++) {
    int nd = snode[p];
    unsigned int u = H[(size_t)nd * 64 + lane];
    float h0 = bf_lo(u), h1 = bf_hi(u);
    float pn = fmaxf(sqrtf(wave_sum(h0 * h0 + h1 * h1)), MINNORM);
    float ps = 1.0f, n = pn;
    if (n > MAXN) { ps = MAXN / n; n = MAXN; }
    float ls = atanhf(fminf(n, CLIPV)) / n * ps;
    m0 += ls * h0;
    m1 += ls * h1;
  }
  float c = fmaxf((float)cnt, 1.0f);
  m0 /= c; m1 /= c;
  float un = fmaxf(sqrtf(wave_sum(m0 * m0 + m1 * m1)), MINNORM);
  float t = tanhf(un);
  float sc = t / un;
  if (t > MAXN) sc *= MAXN / t;
  *reinterpret_cast<float2*>(&out[(size_t)s * 128 + lane * 2]) =
      make_float2(sc * m0, sc * m1);
}

extern "C" void kernel_launch(void* const* d_in, const int* in_sizes, int n_in,
                              void* d_out, int out_size, void* d_ws, size_t ws_size,
                              hipStream_t stream) {
  const float* x  = (const float*)d_in[0];
  const int* erow = (const int*)d_in[1];
  const int* ecol = (const int*)d_in[2];
  const int* seg  = (const int*)d_in[3];
  const float* W1 = (const float*)d_in[4];
  const float* b1 = (const float*)d_in[5];
  const float* W2 = (const float*)d_in[6];
  const float* b2 = (const float*)d_in[7];
  float* out = (float*)d_out;

  const int N = 100000, E = 1600000, S = 1600;

  float* W = (float*)d_ws;
  float* xnbuf = W;                     // N
  float* xn2   = W + 100000;            // N
  float* hb1   = W + 200000;            // 128
  float* hb2   = W + 200128;            // 128
  float* y21   = W + 200256;            // 1
  float* y22   = W + 200260;            // 1
  float* G     = W + 200320;            // N*128 fp32 (GEMM out)
  unsigned int* HT = (unsigned int*)(G + 12800000);   // N*64 (bf16 x2)
  unsigned int* CB = HT + 6400000;      // N*64 (bf16 x2)
  // counters (one contiguous memset region)
  int* hcnt    = (int*)(CB + 6400000);  // N
  int* fill    = hcnt + 100000;         // N
  int* scnt    = fill + 100000;         // S
  int* sfil    = scnt + 1600;           // S
  // non-reset
  int* rowptr  = sfil + 1600;           // N+1
  int* bsum    = rowptr + 100001;       // 256
  int* sptr    = bsum + 256;            // S+1
  int* snode   = sptr + 1601;           // N
  int* colidx  = snode + 100000;        // E

  dim3 blk(256);
  int rowBlocks  = (N + 3) / 4;
  int gemmBlocks = (N + 127) / 128;
  int edgeBlocks = (E + 255) / 256;
  int nodeBlocks = (N + 255) / 256;
  int scanBlocks = (N + 1023) / 1024;

  // ---- CSR builds (edge adjacency + segment membership) ----
  hipMemsetAsync(hcnt, 0, (size_t)(200000 + 3200) * sizeof(int), stream);
  hist_kernel<<<edgeBlocks, blk, 0, stream>>>(erow, hcnt, E);
  scan_kernel<<<scanBlocks, blk, 0, stream>>>(hcnt, rowptr, bsum, N);
  scan_kernel<<<1, blk, 0, stream>>>(bsum, bsum, nullptr, scanBlocks);
  scan_add_kernel<<<nodeBlocks, blk, 0, stream>>>(rowptr, bsum, N, E);
  fill_kernel<<<edgeBlocks, blk, 0, stream>>>(erow, ecol, rowptr, fill, colidx, E);
  hist_kernel<<<nodeBlocks, blk, 0, stream>>>(seg, scnt, N);
  sscan_kernel<<<1, blk, 0, stream>>>(scnt, sptr, S);
  sfill_kernel<<<nodeBlocks, blk, 0, stream>>>(seg, sptr, sfil, snode, N);

  bias_kernel<<<1, 64, 0, stream>>>(b1, hb1, y21);
  bias_kernel<<<1, 64, 0, stream>>>(b2, hb2, y22);

  // ---- layer 1 ----
  gemm_mfma<true><<<gemmBlocks, blk, 0, stream>>>(x, W1, G, xnbuf, N, 256);
  post_gemm_kernel<<<rowBlocks, blk, 0, stream>>>(G, xnbuf, hb1, y21, HT, N);
  agg_gather_act_kernel<<<rowBlocks, blk, 0, stream>>>(HT, rowptr, colidx, CB, xn2, N);

  // ---- layer 2 ----
  gemm_mfma<false><<<gemmBlocks, blk, 0, stream>>>(CB, W2, G, nullptr, N, 128);
  post_gemm_kernel<<<rowBlocks, blk, 0, stream>>>(G, xn2, hb2, y22, HT, N);
  agg_gather_act_kernel<<<rowBlocks, blk, 0, stream>>>(HT, rowptr, colidx, CB, xn2, N);

  // ---- pooling (deterministic gather, no atomics) ----
  pool_gather_kernel<<<(S + 3) / 4, blk, 0, stream>>>(CB, sptr, snode, out, S);
}

// Round 5
// 690.597 us; speedup vs baseline: 1.2438x; 1.2438x over previous
//
#include <hip/hip_runtime.h>

// ---------------------------------------------------------------------------
// HypComEnc: 2-layer hyperbolic GCN encoder + segment mean pool (c = 1)
// N=100000, D0=256, D=128, E=1600000 edges, S=1600 segments
// Round 5: post_gemm fused into GEMM epilogue (2-scalar form), 4-edge-group
//          gather, block-per-segment pool, fewer launches.
// ---------------------------------------------------------------------------

#define MAXN 0.996f          // 1 - PROJ_EPS
#define CLIPV 0.9999999f     // 1 - 1e-7 (artanh clip)
#define MINNORM 1e-15f

typedef __attribute__((ext_vector_type(8))) short  short8;
typedef __attribute__((ext_vector_type(4))) float  f32x4;
typedef __attribute__((ext_vector_type(4))) unsigned short us4;

__device__ __forceinline__ float wave_sum(float v) {
#pragma unroll
  for (int o = 32; o > 0; o >>= 1) v += __shfl_xor(v, o);
  return v;
}
__device__ __forceinline__ float sum16(float v) {
#pragma unroll
  for (int o = 8; o > 0; o >>= 1) v += __shfl_xor(v, o);
  return v;
}

__device__ __forceinline__ unsigned short f2bf(float f) {
  unsigned int u = __float_as_uint(f);
  u = (u + 0x7FFFu + ((u >> 16) & 1u)) >> 16;   // RNE
  return (unsigned short)u;
}
__device__ __forceinline__ float bf_lo(unsigned int u) {
  return __uint_as_float(u << 16);
}
__device__ __forceinline__ float bf_hi(unsigned int u) {
  return __uint_as_float(u & 0xFFFF0000u);
}

// --- hb = proj(expmap0(b)), y2 = ||hb||^2 ; grid 2 x 64 threads -------------
__global__ void bias_kernel(const float* __restrict__ b1i,
                            const float* __restrict__ b2i,
                            float* __restrict__ hb1, float* __restrict__ hb2,
                            float* __restrict__ y21, float* __restrict__ y22) {
  const float* b = blockIdx.x ? b2i : b1i;
  float* hb = blockIdx.x ? hb2 : hb1;
  float* y2o = blockIdx.x ? y22 : y21;
  int lane = threadIdx.x;
  float b0 = b[lane], b1 = b[lane + 64];
  float ssq = wave_sum(b0 * b0 + b1 * b1);
  float un = fmaxf(sqrtf(ssq), MINNORM);
  float t = tanhf(un);
  float s = t / un;
  float n = t;
  if (n > MAXN) { s *= MAXN / n; n = MAXN; }
  hb[lane] = s * b0;
  hb[lane + 64] = s * b1;
  if (lane == 0) y2o[0] = n * n;
}

// --- generic histogram ------------------------------------------------------
__global__ void hist_kernel(const int* __restrict__ keys, int* __restrict__ cnt,
                            int n) {
  int e = blockIdx.x * 256 + threadIdx.x;
  if (e < n) atomicAdd(&cnt[keys[e]], 1);
}

// multi-block scan: 256 thr x 4 elems/block; bsum = per-block totals
__global__ __launch_bounds__(256) void scan_kernel(const int* __restrict__ in,
                                                   int* __restrict__ out,
                                                   int* __restrict__ bsum, int n) {
  __shared__ int sh[256];
  int t = threadIdx.x;
  int base = blockIdx.x * 1024 + t * 4;
  int v0 = 0, v1 = 0, v2 = 0, v3 = 0;
  if (base + 0 < n) v0 = in[base + 0];
  if (base + 1 < n) v1 = in[base + 1];
  if (base + 2 < n) v2 = in[base + 2];
  if (base + 3 < n) v3 = in[base + 3];
  int s = v0 + v1 + v2 + v3;
  sh[t] = s;
  __syncthreads();
  int run = s;
  for (int o = 1; o < 256; o <<= 1) {
    int add = (t >= o) ? sh[t - o] : 0;
    __syncthreads();
    run += add;
    sh[t] = run;
    __syncthreads();
  }
  int excl = run - s;
  if (base + 0 < n) out[base + 0] = excl;
  if (base + 1 < n) out[base + 1] = excl + v0;
  if (base + 2 < n) out[base + 2] = excl + v0 + v1;
  if (base + 3 < n) out[base + 3] = excl + v0 + v1 + v2;
  if (t == 255 && bsum) bsum[blockIdx.x] = run;
}

__global__ void scan_add_kernel(int* __restrict__ pre, const int* __restrict__ boff,
                                int n, int total) {
  int i = blockIdx.x * 256 + threadIdx.x;
  if (i < n) pre[i] += boff[blockIdx.x >> 2];
  if (i == 0) pre[n] = total;
}

// single-block scan for n <= 2048 (segments)
__global__ __launch_bounds__(256) void sscan_kernel(const int* __restrict__ in,
                                                    int* __restrict__ out, int n) {
  __shared__ int sh[256];
  int t = threadIdx.x;
  int base = t * 8;
  int v[8];
  int s = 0;
#pragma unroll
  for (int i = 0; i < 8; i++) {
    v[i] = (base + i < n) ? in[base + i] : 0;
    s += v[i];
  }
  sh[t] = s;
  __syncthreads();
  int run = s;
  for (int o = 1; o < 256; o <<= 1) {
    int add = (t >= o) ? sh[t - o] : 0;
    __syncthreads();
    run += add;
    sh[t] = run;
    __syncthreads();
  }
  int running = run - s;
#pragma unroll
  for (int i = 0; i < 8; i++) {
    if (base + i < n) out[base + i] = running;
    running += v[i];
  }
  if (t == 255) out[n] = running;
}

__global__ void fill_kernel(const int* __restrict__ erow, const int* __restrict__ ecol,
                            const int* __restrict__ rowptr, int* __restrict__ fill,
                            int* __restrict__ colidx, int E) {
  int e = blockIdx.x * 256 + threadIdx.x;
  if (e >= E) return;
  int r = erow[e];
  int pos = rowptr[r] + atomicAdd(&fill[r], 1);
  colidx[pos] = ecol[e];
}

__global__ void sfill_kernel(const int* __restrict__ seg,
                             const int* __restrict__ sptr, int* __restrict__ sfil,
                             int* __restrict__ snode, int M) {
  int i = blockIdx.x * 256 + threadIdx.x;
  if (i >= M) return;
  int s = seg[i];
  int pos = sptr[s] + atomicAdd(&sfil[s], 1);
  snode[pos] = i;
}

// --- fused GEMM + hyperbolic linear tail ------------------------------------
// acc = A@W^T (bf16 MFMA, 128x128 tile, 4 waves, BK=32). Epilogue computes
// out = A_row*acc + B_row*hb  fully in-register/LDS, writes packed-bf16 HT.
// L1: A = fp32 x (row ssq accumulated during staging; f applied post-GEMM).
// L2: A = packed bf16; row norm xn read from xnin (written by gather).
template <bool L1>
__global__ __launch_bounds__(256) void gemm_fused(const void* __restrict__ Xv,
                                                  const float* __restrict__ Wt,
                                                  const float* __restrict__ hb_g,
                                                  const float* __restrict__ y2_g,
                                                  const float* __restrict__ xnin,
                                                  unsigned short* __restrict__ HT,
                                                  int M, int K) {
  constexpr int GS = 128 * 16 + 16;          // 2064 B group stride
  __shared__ alignas(16) char smem[8 * GS];  // A: groups 0..3, B: groups 4..7
  __shared__ float hbs[128];
  __shared__ float redS[128][2], redD[128][2];
  __shared__ float rowA[128], rowB[128];
  __shared__ float fsh[128], xsh[128];
  char* sA = smem;
  char* sB = smem + 4 * GS;
  int tid = threadIdx.x;
  int lane = tid & 63;
  int w = tid >> 6;
  int wr = w >> 1, wc = w & 1;
  int m0 = blockIdx.x * 128;

  if (tid < 128) hbs[tid] = hb_g[tid];

  float ssqr[4] = {0.f, 0.f, 0.f, 0.f};
  f32x4 acc[4][4] = {};
  for (int k0 = 0; k0 < K; k0 += 32) {
#pragma unroll
    for (int j = 0; j < 4; j++) {
      int i = tid + 256 * j;
      int row = i >> 3;
      int koff = (i & 7) * 4;
      int gm = m0 + row;
      us4 av;
      if constexpr (L1) {
        if (gm < M) {
          float4 v = *reinterpret_cast<const float4*>(
              &((const float*)Xv)[(size_t)gm * K + k0 + koff]);
          ssqr[j] += v.x * v.x + v.y * v.y + v.z * v.z + v.w * v.w;
          av[0] = f2bf(v.x); av[1] = f2bf(v.y); av[2] = f2bf(v.z); av[3] = f2bf(v.w);
        } else { av[0] = 0; av[1] = 0; av[2] = 0; av[3] = 0; }
      } else {
        if (gm < M) av = *reinterpret_cast<const us4*>(
            &((const unsigned short*)Xv)[(size_t)gm * K + k0 + koff]);
        else { av[0] = 0; av[1] = 0; av[2] = 0; av[3] = 0; }
      }
      *reinterpret_cast<us4*>(&sA[(koff >> 3) * GS + row * 16 + (koff & 7) * 2]) = av;
      float4 wv = *reinterpret_cast<const float4*>(&Wt[(size_t)row * K + k0 + koff]);
      us4 bv;
      bv[0] = f2bf(wv.x); bv[1] = f2bf(wv.y); bv[2] = f2bf(wv.z); bv[3] = f2bf(wv.w);
      *reinterpret_cast<us4*>(&sB[(koff >> 3) * GS + row * 16 + (koff & 7) * 2]) = bv;
    }
    __syncthreads();
    int g = lane >> 4, r = lane & 15;
    short8 af[4], bfr[4];
#pragma unroll
    for (int mb = 0; mb < 4; mb++)
      af[mb] = *reinterpret_cast<const short8*>(
          &sA[g * GS + (wr * 64 + mb * 16 + r) * 16]);
#pragma unroll
    for (int nb = 0; nb < 4; nb++)
      bfr[nb] = *reinterpret_cast<const short8*>(
          &sB[g * GS + (wc * 64 + nb * 16 + r) * 16]);
#pragma unroll
    for (int mb = 0; mb < 4; mb++)
#pragma unroll
      for (int nb = 0; nb < 4; nb++)
        acc[mb][nb] = __builtin_amdgcn_mfma_f32_16x16x32_bf16(
            af[mb], bfr[nb], acc[mb][nb], 0, 0, 0);
    __syncthreads();
  }

  // --- L1: per-row f, xn from staged ssq (8 consecutive threads per row) ---
  if constexpr (L1) {
#pragma unroll
    for (int j = 0; j < 4; j++) {
      float s = ssqr[j];
      s += __shfl_xor(s, 1); s += __shfl_xor(s, 2); s += __shfl_xor(s, 4);
      if ((tid & 7) == 0) {
        int row = (tid >> 3) + 32 * j;
        float un = fmaxf(sqrtf(s), MINNORM);
        float t = tanhf(un);
        float f, xn;
        if (t > MAXN) { f = MAXN / un; xn = MAXN; }
        else          { f = t / un;    xn = t; }
        fsh[row] = f; xsh[row] = xn;
      }
    }
  }

  // --- phase 1: per-row ||acc||^2 and <acc,hb> (shfl over cc + LDS) --------
  int cr = lane >> 4, cc = lane & 15;
#pragma unroll
  for (int mb = 0; mb < 4; mb++)
#pragma unroll
    for (int q = 0; q < 4; q++) {
      float ps = 0.f, dp = 0.f;
#pragma unroll
      for (int nb = 0; nb < 4; nb++) {
        float a = acc[mb][nb][q];
        ps = fmaf(a, a, ps);
        dp = fmaf(a, hbs[wc * 64 + nb * 16 + cc], dp);
      }
      ps += __shfl_xor(ps, 1); ps += __shfl_xor(ps, 2);
      ps += __shfl_xor(ps, 4); ps += __shfl_xor(ps, 8);
      dp += __shfl_xor(dp, 1); dp += __shfl_xor(dp, 2);
      dp += __shfl_xor(dp, 4); dp += __shfl_xor(dp, 8);
      if (cc == 0) {
        int row = wr * 64 + mb * 16 + cr * 4 + q;
        redS[row][wc] = ps;
        redD[row][wc] = dp;
      }
    }
  __syncthreads();

  // --- phase 2: per-row scalar chain -> A,B ---------------------------------
  if (tid < 128) {
    int gm = m0 + tid;
    float mx2 = redS[tid][0] + redS[tid][1];
    float dp  = redD[tid][0] + redD[tid][1];
    float f, xn;
    if constexpr (L1) { f = fsh[tid]; xn = xsh[tid]; }
    else { f = 1.0f; xn = (gm < M) ? xnin[gm] : 0.5f; }
    float mxn = fmaxf(f * sqrtf(mx2), MINNORM);
    float art = atanhf(fminf(xn, CLIPV));
    float tt = tanhf(mxn / xn * art);
    float s_sc = tt / mxn;
    float rn = tt;
    if (rn > MAXN) { s_sc *= MAXN / rn; rn = MAXN; }
    float SA = s_sc * f;                 // v = SA * acc
    float x2 = rn * rn;
    float xy = SA * dp;                  // <v, hb>
    float y2 = y2_g[0];
    float ca = 1.0f + 2.0f * xy + y2;
    float cb = 1.0f - x2;
    float den = fmaxf(1.0f + 2.0f * xy + x2 * y2, MINNORM);
    float hn2 = ca * ca * x2 + 2.0f * ca * cb * xy + cb * cb * y2;
    float hn = fmaxf(sqrtf(fmaxf(hn2, 0.f)) / den, MINNORM);
    float ps2 = 1.0f, n = hn;
    if (n > MAXN) { ps2 = MAXN / n; n = MAXN; }
    float ls = atanhf(fminf(n, CLIPV)) / n * ps2;   // logmap0(proj(.)) factor
    rowA[tid] = ls * ca * SA / den;
    rowB[tid] = ls * cb / den;
  }
  __syncthreads();

  // --- phase 3: out = A*acc + B*hb, packed bf16 stores ----------------------
#pragma unroll
  for (int mb = 0; mb < 4; mb++)
#pragma unroll
    for (int q = 0; q < 4; q++) {
      int row = wr * 64 + mb * 16 + cr * 4 + q;
      int gm = m0 + row;
      if (gm >= M) continue;
      float A = rowA[row], B = rowB[row];
#pragma unroll
      for (int nb = 0; nb < 4; nb++) {
        int col = wc * 64 + nb * 16 + cc;
        float hv = fmaf(A, acc[mb][nb][q], B * hbs[col]);
        HT[(size_t)gm * 128 + col] = f2bf(hv);
      }
    }
}

// --- CSR gather + fused activation: 4 edge-groups x 16 lanes x 8 features ---
__global__ void agg_gather_act_kernel(const unsigned int* __restrict__ ht,
                                      const int* __restrict__ rowptr,
                                      const int* __restrict__ colidx,
                                      unsigned int* __restrict__ out,
                                      float* __restrict__ xn2, int M) {
  int row = blockIdx.x * 4 + (threadIdx.x >> 6);
  int lane = threadIdx.x & 63;
  if (row >= M) return;
  int g = lane >> 4;         // edge slot in group of 4
  int c16 = lane & 15;       // feature slot: 8 features at uint-offset c16*4
  int p0 = rowptr[row], pe = rowptr[row + 1];
  float a0 = 0.f, a1 = 0.f, a2 = 0.f, a3 = 0.f;
  float a4 = 0.f, a5 = 0.f, a6 = 0.f, a7 = 0.f;
  for (int p = p0 + g; p < pe; p += 4) {
    int c = colidx[p];
    uint4 u = *reinterpret_cast<const uint4*>(&ht[(size_t)c * 64 + c16 * 4]);
    a0 += bf_lo(u.x); a1 += bf_hi(u.x);
    a2 += bf_lo(u.y); a3 += bf_hi(u.y);
    a4 += bf_lo(u.z); a5 += bf_hi(u.z);
    a6 += bf_lo(u.w); a7 += bf_hi(u.w);
  }
  // merge 4 edge-groups (xor 16, then 32)
#pragma unroll
  for (int o = 16; o <= 32; o <<= 1) {
    a0 += __shfl_xor(a0, o); a1 += __shfl_xor(a1, o);
    a2 += __shfl_xor(a2, o); a3 += __shfl_xor(a3, o);
    a4 += __shfl_xor(a4, o); a5 += __shfl_xor(a5, o);
    a6 += __shfl_xor(a6, o); a7 += __shfl_xor(a7, o);
  }
  float ssq = a0 * a0 + a1 * a1 + a2 * a2 + a3 * a3 +
              a4 * a4 + a5 * a5 + a6 * a6 + a7 * a7;
  float an = fmaxf(sqrtf(sum16(ssq)), MINNORM);
  float t = tanhf(an);
  float s = t / an;
  float hn = t;
  if (hn > MAXN) { s *= MAXN / hn; hn = MAXN; }
  float ls = atanhf(fminf(hn, CLIPV)) / hn;
  float sc = ls * s;
  float at0 = tanhf(sc * a0), at1 = tanhf(sc * a1);
  float at2 = tanhf(sc * a2), at3 = tanhf(sc * a3);
  float at4 = tanhf(sc * a4), at5 = tanhf(sc * a5);
  float at6 = tanhf(sc * a6), at7 = tanhf(sc * a7);
  float ssq2 = at0 * at0 + at1 * at1 + at2 * at2 + at3 * at3 +
               at4 * at4 + at5 * at5 + at6 * at6 + at7 * at7;
  float an2 = fmaxf(sqrtf(sum16(ssq2)), MINNORM);
  float t2 = tanhf(an2);
  float s2 = t2 / an2;
  float rn = t2;
  if (t2 > MAXN) { s2 *= MAXN / t2; rn = MAXN; }
  if (g == 0) {
    uint4 o;
    o.x = (unsigned int)f2bf(s2 * at0) | ((unsigned int)f2bf(s2 * at1) << 16);
    o.y = (unsigned int)f2bf(s2 * at2) | ((unsigned int)f2bf(s2 * at3) << 16);
    o.z = (unsigned int)f2bf(s2 * at4) | ((unsigned int)f2bf(s2 * at5) << 16);
    o.w = (unsigned int)f2bf(s2 * at6) | ((unsigned int)f2bf(s2 * at7) << 16);
    *reinterpret_cast<uint4*>(&out[(size_t)row * 64 + c16 * 4]) = o;
    if (c16 == 0) xn2[row] = rn;
  }
}

// --- segment pool: block (4 waves) per segment ------------------------------
__global__ __launch_bounds__(256) void pool_gather_kernel(
    const unsigned int* __restrict__ H, const int* __restrict__ sptr,
    const int* __restrict__ snode, float* __restrict__ out, int S) {
  __shared__ float2 part[4][64];
  int s = blockIdx.x;
  if (s >= S) return;
  int w = threadIdx.x >> 6, lane = threadIdx.x & 63;
  int p0 = sptr[s], pe = sptr[s + 1];
  float m0 = 0.f, m1 = 0.f;
  for (int p = p0 + w; p < pe; p += 4) {
    int nd = snode[p];
    unsigned int u = H[(size_t)nd * 64 + lane];
    float h0 = bf_lo(u), h1 = bf_hi(u);
    float pn = fmaxf(sqrtf(wave_sum(h0 * h0 + h1 * h1)), MINNORM);
    float psc = 1.0f, n = pn;
    if (n > MAXN) { psc = MAXN / n; n = MAXN; }
    float ls = atanhf(fminf(n, CLIPV)) / n * psc;
    m0 += ls * h0;
    m1 += ls * h1;
  }
  part[w][lane] = make_float2(m0, m1);
  __syncthreads();
  if (w == 0) {
    float2 a = part[0][lane], b = part[1][lane];
    float2 c = part[2][lane], d = part[3][lane];
    m0 = a.x + b.x + c.x + d.x;
    m1 = a.y + b.y + c.y + d.y;
    float cn = fmaxf((float)(pe - p0), 1.0f);
    m0 /= cn; m1 /= cn;
    float un = fmaxf(sqrtf(wave_sum(m0 * m0 + m1 * m1)), MINNORM);
    float t = tanhf(un);
    float sc = t / un;
    if (t > MAXN) sc *= MAXN / t;
    *reinterpret_cast<float2*>(&out[(size_t)s * 128 + lane * 2]) =
        make_float2(sc * m0, sc * m1);
  }
}

extern "C" void kernel_launch(void* const* d_in, const int* in_sizes, int n_in,
                              void* d_out, int out_size, void* d_ws, size_t ws_size,
                              hipStream_t stream) {
  const float* x  = (const float*)d_in[0];
  const int* erow = (const int*)d_in[1];
  const int* ecol = (const int*)d_in[2];
  const int* seg  = (const int*)d_in[3];
  const float* W1 = (const float*)d_in[4];
  const float* b1 = (const float*)d_in[5];
  const float* W2 = (const float*)d_in[6];
  const float* b2 = (const float*)d_in[7];
  float* out = (float*)d_out;

  const int N = 100000, E = 1600000, S = 1600;

  float* W = (float*)d_ws;
  float* xn2   = W;                     // N
  float* hb1   = W + 100000;            // 128
  float* hb2   = W + 100128;            // 128
  float* y21   = W + 100256;            // 1
  float* y22   = W + 100260;            // 1
  unsigned int* HT = (unsigned int*)(W + 100352);     // N*64 (bf16 x2)
  unsigned int* CB = HT + 6400000;      // N*64 (bf16 x2)
  // counters (one contiguous memset region: 203200 ints)
  int* hcnt    = (int*)(CB + 6400000);  // N
  int* fill    = hcnt + 100000;         // N
  int* scnt    = fill + 100000;         // S
  int* sfil    = scnt + 1600;           // S
  // non-reset
  int* rowptr  = sfil + 1600;           // N+1
  int* bsum    = rowptr + 100001;       // 256
  int* sptr    = bsum + 256;            // S+1
  int* snode   = sptr + 1601;           // N
  int* colidx  = snode + 100000;        // E

  dim3 blk(256);
  int rowBlocks  = (N + 3) / 4;
  int gemmBlocks = (N + 127) / 128;
  int edgeBlocks = (E + 255) / 256;
  int nodeBlocks = (N + 255) / 256;
  int scanBlocks = (N + 1023) / 1024;

  // ---- CSR builds (edge adjacency + segment membership) ----
  hipMemsetAsync(hcnt, 0, (size_t)(200000 + 3200) * sizeof(int), stream);
  hist_kernel<<<edgeBlocks, blk, 0, stream>>>(erow, hcnt, E);
  scan_kernel<<<scanBlocks, blk, 0, stream>>>(hcnt, rowptr, bsum, N);
  scan_kernel<<<1, blk, 0, stream>>>(bsum, bsum, nullptr, scanBlocks);
  scan_add_kernel<<<nodeBlocks, blk, 0, stream>>>(rowptr, bsum, N, E);
  fill_kernel<<<edgeBlocks, blk, 0, stream>>>(erow, ecol, rowptr, fill, colidx, E);
  hist_kernel<<<nodeBlocks, blk, 0, stream>>>(seg, scnt, N);
  sscan_kernel<<<1, blk, 0, stream>>>(scnt, sptr, S);
  sfill_kernel<<<nodeBlocks, blk, 0, stream>>>(seg, sptr, sfil, snode, N);

  bias_kernel<<<2, 64, 0, stream>>>(b1, b2, hb1, hb2, y21, y22);

  // ---- layer 1 (GEMM + hyperbolic tail fused) ----
  gemm_fused<true><<<gemmBlocks, blk, 0, stream>>>(
      x, W1, hb1, y21, nullptr, (unsigned short*)HT, N, 256);
  agg_gather_act_kernel<<<rowBlocks, blk, 0, stream>>>(HT, rowptr, colidx, CB, xn2, N);

  // ---- layer 2 ----
  gemm_fused<false><<<gemmBlocks, blk, 0, stream>>>(
      CB, W2, hb2, y22, xn2, (unsigned short*)HT, N, 128);
  agg_gather_act_kernel<<<rowBlocks, blk, 0, stream>>>(HT, rowptr, colidx, CB, xn2, N);

  // ---- pooling (block per segment, no atomics) ----
  pool_gather_kernel<<<S, blk, 0, stream>>>(CB, sptr, snode, out, S);
}

// Round 6
// 634.631 us; speedup vs baseline: 1.3535x; 1.0882x over previous
//
#include <hip/hip_runtime.h>

// ---------------------------------------------------------------------------
// HypComEnc: 2-layer hyperbolic GCN encoder + segment mean pool (c = 1)
// N=100000, D0=256, D=128, E=1600000 edges, S=1600 segments
// Round 6: BK=64 GEMM, pre-converted bf16 W, cvt_pk staging, fused small
//          kernels (15 -> 11 launches).
// ---------------------------------------------------------------------------

#define MAXN 0.996f          // 1 - PROJ_EPS
#define CLIPV 0.9999999f     // 1 - 1e-7 (artanh clip)
#define MINNORM 1e-15f

typedef __attribute__((ext_vector_type(8))) short  short8;
typedef __attribute__((ext_vector_type(4))) float  f32x4;

__device__ __forceinline__ float wave_sum(float v) {
#pragma unroll
  for (int o = 32; o > 0; o >>= 1) v += __shfl_xor(v, o);
  return v;
}
__device__ __forceinline__ float sum16(float v) {
#pragma unroll
  for (int o = 8; o > 0; o >>= 1) v += __shfl_xor(v, o);
  return v;
}

__device__ __forceinline__ unsigned short f2bf(float f) {
  unsigned int u = __float_as_uint(f);
  u = (u + 0x7FFFu + ((u >> 16) & 1u)) >> 16;   // RNE
  return (unsigned short)u;
}
__device__ __forceinline__ float bf_lo(unsigned int u) {
  return __uint_as_float(u << 16);
}
__device__ __forceinline__ float bf_hi(unsigned int u) {
  return __uint_as_float(u & 0xFFFF0000u);
}
// packed f32x2 -> bf16x2 (low = first arg)  [T12 recipe: no builtin on gfx950]
__device__ __forceinline__ unsigned int cvt2(float lo, float hi) {
  unsigned int r;
  asm("v_cvt_pk_bf16_f32 %0, %1, %2" : "=v"(r) : "v"(lo), "v"(hi));
  return r;
}

// --- setup: edge hist + seg hist + W->bf16 + bias, grid-partitioned ---------
__global__ __launch_bounds__(256) void setup_kernel(
    const int* __restrict__ erow, const int* __restrict__ seg,
    const float* __restrict__ b1, const float* __restrict__ b2,
    const float* __restrict__ W1, const float* __restrict__ W2,
    int* __restrict__ hcnt, int* __restrict__ scnt,
    float* __restrict__ hb1, float* __restrict__ hb2,
    float* __restrict__ y21, float* __restrict__ y22,
    unsigned short* __restrict__ Wb1, unsigned short* __restrict__ Wb2) {
  const int EB = 6250, NB = 391, WB = 192;
  int b = blockIdx.x, tid = threadIdx.x;
  if (b < EB) {
    int e = b * 256 + tid;
    if (e < 1600000) atomicAdd(&hcnt[erow[e]], 1);
  } else if (b < EB + NB) {
    int i = (b - EB) * 256 + tid;
    if (i < 100000) atomicAdd(&scnt[seg[i]], 1);
  } else if (b < EB + NB + WB) {
    int i = (b - EB - NB) * 256 + tid;
    if (i < 32768) Wb1[i] = f2bf(W1[i]);
    else           Wb2[i - 32768] = f2bf(W2[i - 32768]);
  } else {
    if (tid >= 64) return;
    int which = b - (EB + NB + WB);
    const float* bb = which ? b2 : b1;
    float* hb  = which ? hb2 : hb1;
    float* y2o = which ? y22 : y21;
    float v0 = bb[tid], v1 = bb[tid + 64];
    float ssq = wave_sum(v0 * v0 + v1 * v1);
    float un = fmaxf(sqrtf(ssq), MINNORM);
    float t = tanhf(un);
    float s = t / un;
    float n = t;
    if (n > MAXN) { s *= MAXN / n; n = MAXN; }
    hb[tid] = s * v0;
    hb[tid + 64] = s * v1;
    if (tid == 0) y2o[0] = n * n;
  }
}

// --- scans: blocks 0..97 scan hcnt(100000)->rowptr(+bsum); block 98 scans
//     scnt(1600)->sptr (single-block, writes sptr[1600]=total) ---------------
__global__ __launch_bounds__(256) void scan_both_kernel(
    const int* __restrict__ hcnt, int* __restrict__ rowptr,
    int* __restrict__ bsum, const int* __restrict__ scnt,
    int* __restrict__ sptr) {
  __shared__ int sh[256];
  int t = threadIdx.x;
  if (blockIdx.x < 98) {
    const int n = 100000;
    int base = blockIdx.x * 1024 + t * 4;
    int v0 = 0, v1 = 0, v2 = 0, v3 = 0;
    if (base + 0 < n) v0 = hcnt[base + 0];
    if (base + 1 < n) v1 = hcnt[base + 1];
    if (base + 2 < n) v2 = hcnt[base + 2];
    if (base + 3 < n) v3 = hcnt[base + 3];
    int s = v0 + v1 + v2 + v3;
    sh[t] = s;
    __syncthreads();
    int run = s;
    for (int o = 1; o < 256; o <<= 1) {
      int add = (t >= o) ? sh[t - o] : 0;
      __syncthreads();
      run += add;
      sh[t] = run;
      __syncthreads();
    }
    int excl = run - s;
    if (base + 0 < n) rowptr[base + 0] = excl;
    if (base + 1 < n) rowptr[base + 1] = excl + v0;
    if (base + 2 < n) rowptr[base + 2] = excl + v0 + v1;
    if (base + 3 < n) rowptr[base + 3] = excl + v0 + v1 + v2;
    if (t == 255) bsum[blockIdx.x] = run;
  } else {
    const int n = 1600;
    int base = t * 8;
    int v[8];
    int s = 0;
#pragma unroll
    for (int i = 0; i < 8; i++) {
      v[i] = (base + i < n) ? scnt[base + i] : 0;
      s += v[i];
    }
    sh[t] = s;
    __syncthreads();
    int run = s;
    for (int o = 1; o < 256; o <<= 1) {
      int add = (t >= o) ? sh[t - o] : 0;
      __syncthreads();
      run += add;
      sh[t] = run;
      __syncthreads();
    }
    int running = run - s;
#pragma unroll
    for (int i = 0; i < 8; i++) {
      if (base + i < n) sptr[base + i] = running;
      running += v[i];
    }
    if (t == 255) sptr[n] = running;
  }
}

// single-block scan of bsum (98 entries), in place
__global__ __launch_bounds__(256) void scan_kernel(const int* __restrict__ in,
                                                   int* __restrict__ out, int n) {
  __shared__ int sh[256];
  int t = threadIdx.x;
  int base = t * 4;
  int v0 = 0, v1 = 0, v2 = 0, v3 = 0;
  if (base + 0 < n) v0 = in[base + 0];
  if (base + 1 < n) v1 = in[base + 1];
  if (base + 2 < n) v2 = in[base + 2];
  if (base + 3 < n) v3 = in[base + 3];
  int s = v0 + v1 + v2 + v3;
  sh[t] = s;
  __syncthreads();
  int run = s;
  for (int o = 1; o < 256; o <<= 1) {
    int add = (t >= o) ? sh[t - o] : 0;
    __syncthreads();
    run += add;
    sh[t] = run;
    __syncthreads();
  }
  int excl = run - s;
  if (base + 0 < n) out[base + 0] = excl;
  if (base + 1 < n) out[base + 1] = excl + v0;
  if (base + 2 < n) out[base + 2] = excl + v0 + v1;
  if (base + 3 < n) out[base + 3] = excl + v0 + v1 + v2;
}

__global__ void scan_add_kernel(int* __restrict__ pre, const int* __restrict__ boff,
                                int n, int total) {
  int i = blockIdx.x * 256 + threadIdx.x;
  if (i < n) pre[i] += boff[blockIdx.x >> 2];
  if (i == 0) pre[n] = total;
}

// --- placement: blocks 0..6249 edge fill; 6250..6640 segment fill -----------
__global__ void fill_both_kernel(const int* __restrict__ erow,
                                 const int* __restrict__ ecol,
                                 const int* __restrict__ rowptr,
                                 int* __restrict__ fill, int* __restrict__ colidx,
                                 const int* __restrict__ seg,
                                 const int* __restrict__ sptr,
                                 int* __restrict__ sfil, int* __restrict__ snode) {
  int b = blockIdx.x, tid = threadIdx.x;
  if (b < 6250) {
    int e = b * 256 + tid;
    if (e >= 1600000) return;
    int r = erow[e];
    int pos = rowptr[r] + atomicAdd(&fill[r], 1);
    colidx[pos] = ecol[e];
  } else {
    int i = (b - 6250) * 256 + tid;
    if (i >= 100000) return;
    int s = seg[i];
    int pos = sptr[s] + atomicAdd(&sfil[s], 1);
    snode[pos] = i;
  }
}

// --- fused GEMM + hyperbolic linear tail, BK=64 -----------------------------
// acc = A@W^T (bf16 MFMA, 128x128 tile, 4 waves). Epilogue computes
// out = A_row*acc + B_row*hb in-register/LDS, writes packed-bf16 HT.
// L1: A = fp32 x (ssq accumulated during staging, cvt_pk convert).
// L2: A = packed bf16; row norm from xnin. W pre-converted bf16 (Wb).
template <bool L1>
__global__ __launch_bounds__(256) void gemm_fused(const void* __restrict__ Xv,
                                                  const unsigned short* __restrict__ Wb,
                                                  const float* __restrict__ hb_g,
                                                  const float* __restrict__ y2_g,
                                                  const float* __restrict__ xnin,
                                                  unsigned short* __restrict__ HT,
                                                  int M, int K) {
  constexpr int GS = 128 * 16 + 16;          // 2064 B per k-group
  __shared__ alignas(16) char smem[16 * GS]; // A: groups 0..7, B: 8..15 (33KB)
  __shared__ float hbs[128];
  __shared__ float redS[128][2], redD[128][2];
  __shared__ float rowA[128], rowB[128];
  __shared__ float fsh[128], xsh[128];
  char* sA = smem;
  char* sB = smem + 8 * GS;
  int tid = threadIdx.x;
  int lane = tid & 63;
  int w = tid >> 6;
  int wr = w >> 1, wc = w & 1;
  int m0 = blockIdx.x * 128;

  if (tid < 128) hbs[tid] = hb_g[tid];

  int row_s = tid >> 3;   // staging: row (tid>>3)+32j, k-group tid&7
  int kg = tid & 7;
  float ssqr[4] = {0.f, 0.f, 0.f, 0.f};
  f32x4 acc[4][4] = {};
  for (int k0 = 0; k0 < K; k0 += 64) {
#pragma unroll
    for (int j = 0; j < 4; j++) {
      int row = row_s + 32 * j;
      int gm = m0 + row;
      int kb = k0 + kg * 8;
      uint4 av = make_uint4(0, 0, 0, 0);
      if constexpr (L1) {
        if (gm < M) {
          const float* xr = &((const float*)Xv)[(size_t)gm * K + kb];
          float4 v0 = *reinterpret_cast<const float4*>(xr);
          float4 v1 = *reinterpret_cast<const float4*>(xr + 4);
          ssqr[j] += v0.x * v0.x + v0.y * v0.y + v0.z * v0.z + v0.w * v0.w +
                     v1.x * v1.x + v1.y * v1.y + v1.z * v1.z + v1.w * v1.w;
          av.x = cvt2(v0.x, v0.y); av.y = cvt2(v0.z, v0.w);
          av.z = cvt2(v1.x, v1.y); av.w = cvt2(v1.z, v1.w);
        }
      } else {
        if (gm < M) av = *reinterpret_cast<const uint4*>(
            &((const unsigned short*)Xv)[(size_t)gm * K + kb]);
      }
      *reinterpret_cast<uint4*>(&sA[kg * GS + row * 16]) = av;
      uint4 bv = *reinterpret_cast<const uint4*>(&Wb[(size_t)row * K + kb]);
      *reinterpret_cast<uint4*>(&sB[kg * GS + row * 16]) = bv;
    }
    __syncthreads();
    int gh = lane >> 4, r = lane & 15;
#pragma unroll
    for (int kk = 0; kk < 2; kk++) {
      int g2 = kk * 4 + gh;
      short8 af[4], bfv[4];
#pragma unroll
      for (int mb = 0; mb < 4; mb++)
        af[mb] = *reinterpret_cast<const short8*>(
            &sA[g2 * GS + (wr * 64 + mb * 16 + r) * 16]);
#pragma unroll
      for (int nb = 0; nb < 4; nb++)
        bfv[nb] = *reinterpret_cast<const short8*>(
            &sB[g2 * GS + (wc * 64 + nb * 16 + r) * 16]);
#pragma unroll
      for (int mb = 0; mb < 4; mb++)
#pragma unroll
        for (int nb = 0; nb < 4; nb++)
          acc[mb][nb] = __builtin_amdgcn_mfma_f32_16x16x32_bf16(
              af[mb], bfv[nb], acc[mb][nb], 0, 0, 0);
    }
    __syncthreads();
  }

  // --- L1: per-row f, xn from staged ssq (8 consecutive threads per row) ---
  if constexpr (L1) {
#pragma unroll
    for (int j = 0; j < 4; j++) {
      float s = ssqr[j];
      s += __shfl_xor(s, 1); s += __shfl_xor(s, 2); s += __shfl_xor(s, 4);
      if ((tid & 7) == 0) {
        int row = row_s + 32 * j;
        float un = fmaxf(sqrtf(s), MINNORM);
        float t = tanhf(un);
        float f, xn;
        if (t > MAXN) { f = MAXN / un; xn = MAXN; }
        else          { f = t / un;    xn = t; }
        fsh[row] = f; xsh[row] = xn;
      }
    }
  }

  // --- phase 1: per-row ||acc||^2 and <acc,hb> ------------------------------
  int cr = lane >> 4, cc = lane & 15;
#pragma unroll
  for (int mb = 0; mb < 4; mb++)
#pragma unroll
    for (int q = 0; q < 4; q++) {
      float ps = 0.f, dp = 0.f;
#pragma unroll
      for (int nb = 0; nb < 4; nb++) {
        float a = acc[mb][nb][q];
        ps = fmaf(a, a, ps);
        dp = fmaf(a, hbs[wc * 64 + nb * 16 + cc], dp);
      }
      ps += __shfl_xor(ps, 1); ps += __shfl_xor(ps, 2);
      ps += __shfl_xor(ps, 4); ps += __shfl_xor(ps, 8);
      dp += __shfl_xor(dp, 1); dp += __shfl_xor(dp, 2);
      dp += __shfl_xor(dp, 4); dp += __shfl_xor(dp, 8);
      if (cc == 0) {
        int row = wr * 64 + mb * 16 + cr * 4 + q;
        redS[row][wc] = ps;
        redD[row][wc] = dp;
      }
    }
  __syncthreads();

  // --- phase 2: per-row scalar chain -> A,B ---------------------------------
  if (tid < 128) {
    int gm = m0 + tid;
    float mx2 = redS[tid][0] + redS[tid][1];
    float dp  = redD[tid][0] + redD[tid][1];
    float f, xn;
    if constexpr (L1) { f = fsh[tid]; xn = xsh[tid]; }
    else { f = 1.0f; xn = (gm < M) ? xnin[gm] : 0.5f; }
    float mxn = fmaxf(f * sqrtf(mx2), MINNORM);
    float art = atanhf(fminf(xn, CLIPV));
    float tt = tanhf(mxn / xn * art);
    float s_sc = tt / mxn;
    float rn = tt;
    if (rn > MAXN) { s_sc *= MAXN / rn; rn = MAXN; }
    float SA = s_sc * f;                 // v = SA * acc
    float x2 = rn * rn;
    float xy = SA * dp;                  // <v, hb>
    float y2 = y2_g[0];
    float ca = 1.0f + 2.0f * xy + y2;
    float cb = 1.0f - x2;
    float den = fmaxf(1.0f + 2.0f * xy + x2 * y2, MINNORM);
    float hn2 = ca * ca * x2 + 2.0f * ca * cb * xy + cb * cb * y2;
    float hn = fmaxf(sqrtf(fmaxf(hn2, 0.f)) / den, MINNORM);
    float ps2 = 1.0f, n = hn;
    if (n > MAXN) { ps2 = MAXN / n; n = MAXN; }
    float ls = atanhf(fminf(n, CLIPV)) / n * ps2;   // logmap0(proj(.)) factor
    rowA[tid] = ls * ca * SA / den;
    rowB[tid] = ls * cb / den;
  }
  __syncthreads();

  // --- phase 3: out = A*acc + B*hb, packed bf16 stores ----------------------
#pragma unroll
  for (int mb = 0; mb < 4; mb++)
#pragma unroll
    for (int q = 0; q < 4; q++) {
      int row = wr * 64 + mb * 16 + cr * 4 + q;
      int gm = m0 + row;
      if (gm >= M) continue;
      float A = rowA[row], B = rowB[row];
#pragma unroll
      for (int nb = 0; nb < 4; nb++) {
        int col = wc * 64 + nb * 16 + cc;
        float hv = fmaf(A, acc[mb][nb][q], B * hbs[col]);
        HT[(size_t)gm * 128 + col] = f2bf(hv);
      }
    }
}

// --- CSR gather + fused activation: 4 edge-groups x 16 lanes x 8 features ---
__global__ void agg_gather_act_kernel(const unsigned int* __restrict__ ht,
                                      const int* __restrict__ rowptr,
                                      const int* __restrict__ colidx,
                                      unsigned int* __restrict__ out,
                                      float* __restrict__ xn2, int M) {
  int row = blockIdx.x * 4 + (threadIdx.x >> 6);
  int lane = threadIdx.x & 63;
  if (row >= M) return;
  int g = lane >> 4;         // edge slot in group of 4
  int c16 = lane & 15;       // feature slot: 8 features at uint-offset c16*4
  int p0 = rowptr[row], pe = rowptr[row + 1];
  float a0 = 0.f, a1 = 0.f, a2 = 0.f, a3 = 0.f;
  float a4 = 0.f, a5 = 0.f, a6 = 0.f, a7 = 0.f;
  for (int p = p0 + g; p < pe; p += 4) {
    int c = colidx[p];
    uint4 u = *reinterpret_cast<const uint4*>(&ht[(size_t)c * 64 + c16 * 4]);
    a0 += bf_lo(u.x); a1 += bf_hi(u.x);
    a2 += bf_lo(u.y); a3 += bf_hi(u.y);
    a4 += bf_lo(u.z); a5 += bf_hi(u.z);
    a6 += bf_lo(u.w); a7 += bf_hi(u.w);
  }
#pragma unroll
  for (int o = 16; o <= 32; o <<= 1) {
    a0 += __shfl_xor(a0, o); a1 += __shfl_xor(a1, o);
    a2 += __shfl_xor(a2, o); a3 += __shfl_xor(a3, o);
    a4 += __shfl_xor(a4, o); a5 += __shfl_xor(a5, o);
    a6 += __shfl_xor(a6, o); a7 += __shfl_xor(a7, o);
  }
  float ssq = a0 * a0 + a1 * a1 + a2 * a2 + a3 * a3 +
              a4 * a4 + a5 * a5 + a6 * a6 + a7 * a7;
  float an = fmaxf(sqrtf(sum16(ssq)), MINNORM);
  float t = tanhf(an);
  float s = t / an;
  float hn = t;
  if (hn > MAXN) { s *= MAXN / hn; hn = MAXN; }
  float ls = atanhf(fminf(hn, CLIPV)) / hn;
  float sc = ls * s;
  float at0 = tanhf(sc * a0), at1 = tanhf(sc * a1);
  float at2 = tanhf(sc * a2), at3 = tanhf(sc * a3);
  float at4 = tanhf(sc * a4), at5 = tanhf(sc * a5);
  float at6 = tanhf(sc * a6), at7 = tanhf(sc * a7);
  float ssq2 = at0 * at0 + at1 * at1 + at2 * at2 + at3 * at3 +
               at4 * at4 + at5 * at5 + at6 * at6 + at7 * at7;
  float an2 = fmaxf(sqrtf(sum16(ssq2)), MINNORM);
  float t2 = tanhf(an2);
  float s2 = t2 / an2;
  float rn = t2;
  if (t2 > MAXN) { s2 *= MAXN / t2; rn = MAXN; }
  if (g == 0) {
    uint4 o;
    o.x = (unsigned int)f2bf(s2 * at0) | ((unsigned int)f2bf(s2 * at1) << 16);
    o.y = (unsigned int)f2bf(s2 * at2) | ((unsigned int)f2bf(s2 * at3) << 16);
    o.z = (unsigned int)f2bf(s2 * at4) | ((unsigned int)f2bf(s2 * at5) << 16);
    o.w = (unsigned int)f2bf(s2 * at6) | ((unsigned int)f2bf(s2 * at7) << 16);
    *reinterpret_cast<uint4*>(&out[(size_t)row * 64 + c16 * 4]) = o;
    if (c16 == 0) xn2[row] = rn;
  }
}

// --- segment pool: block (4 waves) per segment ------------------------------
__global__ __launch_bounds__(256) void pool_gather_kernel(
    const unsigned int* __restrict__ H, const int* __restrict__ sptr,
    const int* __restrict__ snode, float* __restrict__ out, int S) {
  __shared__ float2 part[4][64];
  int s = blockIdx.x;
  if (s >= S) return;
  int w = threadIdx.x >> 6, lane = threadIdx.x & 63;
  int p0 = sptr[s], pe = sptr[s + 1];
  float m0 = 0.f, m1 = 0.f;
  for (int p = p0 + w; p < pe; p += 4) {
    int nd = snode[p];
    unsigned int u = H[(size_t)nd * 64 + lane];
    float h0 = bf_lo(u), h1 = bf_hi(u);
    float pn = fmaxf(sqrtf(wave_sum(h0 * h0 + h1 * h1)), MINNORM);
    float psc = 1.0f, n = pn;
    if (n > MAXN) { psc = MAXN / n; n = MAXN; }
    float ls = atanhf(fminf(n, CLIPV)) / n * psc;
    m0 += ls * h0;
    m1 += ls * h1;
  }
  part[w][lane] = make_float2(m0, m1);
  __syncthreads();
  if (w == 0) {
    float2 a = part[0][lane], b = part[1][lane];
    float2 c = part[2][lane], d = part[3][lane];
    m0 = a.x + b.x + c.x + d.x;
    m1 = a.y + b.y + c.y + d.y;
    float cn = fmaxf((float)(pe - p0), 1.0f);
    m0 /= cn; m1 /= cn;
    float un = fmaxf(sqrtf(wave_sum(m0 * m0 + m1 * m1)), MINNORM);
    float t = tanhf(un);
    float sc = t / un;
    if (t > MAXN) sc *= MAXN / t;
    *reinterpret_cast<float2*>(&out[(size_t)s * 128 + lane * 2]) =
        make_float2(sc * m0, sc * m1);
  }
}

extern "C" void kernel_launch(void* const* d_in, const int* in_sizes, int n_in,
                              void* d_out, int out_size, void* d_ws, size_t ws_size,
                              hipStream_t stream) {
  const float* x  = (const float*)d_in[0];
  const int* erow = (const int*)d_in[1];
  const int* ecol = (const int*)d_in[2];
  const int* seg  = (const int*)d_in[3];
  const float* W1 = (const float*)d_in[4];
  const float* b1 = (const float*)d_in[5];
  const float* W2 = (const float*)d_in[6];
  const float* b2 = (const float*)d_in[7];
  float* out = (float*)d_out;

  const int N = 100000, E = 1600000, S = 1600;

  float* W = (float*)d_ws;
  float* xn2   = W;                     // N
  float* hb1   = W + 100000;            // 128
  float* hb2   = W + 100128;            // 128
  float* y21   = W + 100256;            // 1
  float* y22   = W + 100260;            // 1
  unsigned short* Wb1 = (unsigned short*)(W + 100352);  // 32768 bf16
  unsigned short* Wb2 = Wb1 + 32768;                    // 16384 bf16
  unsigned int* HT = (unsigned int*)(W + 124928);       // N*64 (bf16 x2)
  unsigned int* CB = HT + 6400000;      // N*64 (bf16 x2)
  // counters (contiguous memset region: 203200 ints)
  int* hcnt    = (int*)(CB + 6400000);  // N
  int* fill    = hcnt + 100000;         // N
  int* scnt    = fill + 100000;         // S
  int* sfil    = scnt + 1600;           // S
  // non-reset
  int* rowptr  = sfil + 1600;           // N+1
  int* bsum    = rowptr + 100001;       // 256
  int* sptr    = bsum + 256;            // S+1
  int* snode   = sptr + 1601;           // N
  int* colidx  = snode + 100000;        // E

  dim3 blk(256);
  int rowBlocks  = (N + 3) / 4;
  int gemmBlocks = (N + 127) / 128;

  // ---- CSR builds + bias + W conversion (fused small kernels) ----
  hipMemsetAsync(hcnt, 0, (size_t)203200 * sizeof(int), stream);
  setup_kernel<<<6250 + 391 + 192 + 2, blk, 0, stream>>>(
      erow, seg, b1, b2, W1, W2, hcnt, scnt, hb1, hb2, y21, y22, Wb1, Wb2);
  scan_both_kernel<<<99, blk, 0, stream>>>(hcnt, rowptr, bsum, scnt, sptr);
  scan_kernel<<<1, blk, 0, stream>>>(bsum, bsum, 98);
  scan_add_kernel<<<(N + 255) / 256, blk, 0, stream>>>(rowptr, bsum, N, E);
  fill_both_kernel<<<6250 + 391, blk, 0, stream>>>(
      erow, ecol, rowptr, fill, colidx, seg, sptr, sfil, snode);

  // ---- layer 1 (GEMM + hyperbolic tail fused) ----
  gemm_fused<true><<<gemmBlocks, blk, 0, stream>>>(
      x, Wb1, hb1, y21, nullptr, (unsigned short*)HT, N, 256);
  agg_gather_act_kernel<<<rowBlocks, blk, 0, stream>>>(HT, rowptr, colidx, CB, xn2, N);

  // ---- layer 2 ----
  gemm_fused<false><<<gemmBlocks, blk, 0, stream>>>(
      CB, Wb2, hb2, y22, xn2, (unsigned short*)HT, N, 128);
  agg_gather_act_kernel<<<rowBlocks, blk, 0, stream>>>(HT, rowptr, colidx, CB, xn2, N);

  // ---- pooling (block per segment, no atomics) ----
  pool_gather_kernel<<<S, blk, 0, stream>>>(CB, sptr, snode, out, S);
}